// Round 3
// baseline (101.732 us; speedup 1.0000x reference)
//
#include <hip/hip_runtime.h>
#include <math.h>

#define NB 32
#define NN 1024
#define NF 512

// ---------------- transpose W[NN][NF] -> Wt[NF][NN] ----------------
__global__ __launch_bounds__(256) void transpose_w_k(const float* __restrict__ W,
                                                     float* __restrict__ Wt) {
    __shared__ float tile[32][33];
    int n0 = blockIdx.x * 32;
    int f0 = blockIdx.y * 32;
    int tx = threadIdx.x & 31;
    int ty = threadIdx.x >> 5;  // 0..7
#pragma unroll
    for (int r = 0; r < 32; r += 8) {
        tile[ty + r][tx] = W[(n0 + ty + r) * NF + (f0 + tx)];
    }
    __syncthreads();
#pragma unroll
    for (int r = 0; r < 32; r += 8) {
        Wt[(f0 + ty + r) * NN + (n0 + tx)] = tile[tx][ty + r];
    }
}

// xor-butterfly: every lane ends with the bitwise-identical value
__device__ __forceinline__ float wave_sum(float v) {
#pragma unroll
    for (int d = 1; d < 64; d <<= 1) v += __shfl_xor(v, d, 64);
    return v;
}
__device__ __forceinline__ float wave_max(float v) {
#pragma unroll
    for (int d = 1; d < 64; d <<= 1) v = fmaxf(v, __shfl_xor(v, d, 64));
    return v;
}

// One wave per output (b,f). Output = relu(u_p - u_m) where u_s is the root of
//   g(u) = sum_n [ relu(u - m_n) + relu(u + m_n) ] = 1,
// m = |x + 0.5W| (plus side), m = |x - 0.5W| (minus side).
// Negative-root regime (Sum m >= 1, always true here): solve F(t) = 1 with
//   F(t) = sum relu(m - t),  u = -t,  t in [0, max m].
// F is convex piecewise-linear; m ~ U(0,1) makes F near-quadratic, so the
// sqrt-model step is ~exact. Fixed 5 hybrid sweeps:
//   E >= 1 (below root): accelerated step 2(E - sqrt(E))/c  (quadratic model)
//   E <  1 (above root): Newton (E - 1)/c  -> lands at/below root (convexity)
// Clamp t in [0, M] => c >= 1 always. All control flow wave-uniform & fixed.
__global__ __launch_bounds__(256) void spike_main_k(const float* __restrict__ x,
                                                    const float* __restrict__ W,
                                                    const float* __restrict__ Wt,
                                                    int use_wt,
                                                    float* __restrict__ out) {
    int bid  = blockIdx.x;
    int b    = bid >> 7;
    int fg   = bid & 127;
    int wave = threadIdx.x >> 6;
    int lane = threadIdx.x & 63;
    int f    = fg * 4 + wave;

    float mp[16], mm[16];
    float sp0 = 0.f, sm0 = 0.f, xp0 = 0.f, xm0 = 0.f;

    if (use_wt) {
        const float4* x4 = reinterpret_cast<const float4*>(x + (size_t)b * NN);
        const float4* w4 = reinterpret_cast<const float4*>(Wt + (size_t)f * NN);
#pragma unroll
        for (int j = 0; j < 4; ++j) {
            float4 xv = x4[lane + 64 * j];
            float4 wv = w4[lane + 64 * j];
            float ap, am;
            ap = fabsf(xv.x + 0.5f * wv.x); am = fabsf(xv.x - 0.5f * wv.x);
            mp[4*j+0] = ap; mm[4*j+0] = am; sp0 += ap; sm0 += am;
            xp0 = fmaxf(xp0, ap); xm0 = fmaxf(xm0, am);
            ap = fabsf(xv.y + 0.5f * wv.y); am = fabsf(xv.y - 0.5f * wv.y);
            mp[4*j+1] = ap; mm[4*j+1] = am; sp0 += ap; sm0 += am;
            xp0 = fmaxf(xp0, ap); xm0 = fmaxf(xm0, am);
            ap = fabsf(xv.z + 0.5f * wv.z); am = fabsf(xv.z - 0.5f * wv.z);
            mp[4*j+2] = ap; mm[4*j+2] = am; sp0 += ap; sm0 += am;
            xp0 = fmaxf(xp0, ap); xm0 = fmaxf(xm0, am);
            ap = fabsf(xv.w + 0.5f * wv.w); am = fabsf(xv.w - 0.5f * wv.w);
            mp[4*j+3] = ap; mm[4*j+3] = am; sp0 += ap; sm0 += am;
            xp0 = fmaxf(xp0, ap); xm0 = fmaxf(xm0, am);
        }
    } else {
#pragma unroll
        for (int j = 0; j < 16; ++j) {
            int n = lane + 64 * j;
            float xv = x[(size_t)b * NN + n];
            float wv = W[(size_t)n * NF + f];
            float ap = fabsf(xv + 0.5f * wv);
            float am = fabsf(xv - 0.5f * wv);
            mp[j] = ap; mm[j] = am;
            sp0 += ap; sm0 += am;
            xp0 = fmaxf(xp0, ap); xm0 = fmaxf(xm0, am);
        }
    }
    float Sp = wave_sum(sp0);
    float Sm = wave_sum(sm0);
    float Mp = wave_max(xp0);
    float Mm = wave_max(xm0);

    const bool neg_p = (Sp >= 1.0f);
    const bool neg_m = (Sm >= 1.0f);

    float up_out, um_out;

    if (neg_p && neg_m) {
        // ---- fast path (always taken for this data): both roots <= 0 ----
        // warm start from the quadratic model at t=0: F(0)=S, F'(0)=-1024
        float tp = fminf(fmaxf(2.0f * (Sp - sqrtf(Sp)) * (1.0f / 1024.0f), 0.0f), Mp);
        float tm = fminf(fmaxf(2.0f * (Sm - sqrtf(Sm)) * (1.0f / 1024.0f), 0.0f), Mm);
#pragma unroll
        for (int s = 0; s < 5; ++s) {
            float ssp = 0.f, ssm = 0.f;
            int cp = 0, cm = 0;
#pragma unroll
            for (int j = 0; j < 16; ++j) {
                bool prp = (mp[j] >= tp);
                bool prm = (mm[j] >= tm);
                cp += (int)__popcll(__ballot(prp));   // SALU pipe
                cm += (int)__popcll(__ballot(prm));
                ssp += prp ? mp[j] : 0.0f;
                ssm += prm ? mm[j] : 0.0f;
            }
            ssp = wave_sum(ssp);
            ssm = wave_sum(ssm);
            float fcp = (float)cp, fcm = (float)cm;     // >= 1 (t <= M)
            float Ep = ssp - tp * fcp;                  // F(tp) >= 0
            float Em = ssm - tm * fcm;
            float dp = (Ep >= 1.0f) ? 2.0f * (Ep - sqrtf(Ep)) : (Ep - 1.0f);
            float dm = (Em >= 1.0f) ? 2.0f * (Em - sqrtf(Em)) : (Em - 1.0f);
            tp = fminf(fmaxf(tp + dp / fcp, 0.0f), Mp);
            tm = fminf(fmaxf(tm + dm / fcm, 0.0f), Mm);
        }
        up_out = -tp;
        um_out = -tm;
    } else {
        // ---- cold path: exact general solver, fixed iteration counts ----
        float res[2];
        const float* marr[2] = {mp, mm};
        float Sv[2] = {Sp, Sm};
        float Mv[2] = {Mp, Mm};
        bool  nv[2] = {neg_p, neg_m};
#pragma unroll 1
        for (int side = 0; side < 2; ++side) {
            const float* m = marr[side];
            if (nv[side]) {
                float t = fminf(fmaxf(2.0f * (Sv[side] - sqrtf(Sv[side])) * (1.0f / 1024.0f), 0.0f), Mv[side]);
#pragma unroll 1
                for (int s = 0; s < 20; ++s) {
                    float ss = 0.f; int c = 0;
#pragma unroll
                    for (int j = 0; j < 16; ++j) {
                        bool pr = (m[j] >= t);
                        c += (int)__popcll(__ballot(pr));
                        ss += pr ? m[j] : 0.0f;
                    }
                    ss = wave_sum(ss);
                    float fc = (float)c;
                    float E = ss - t * fc;
                    float d = (E >= 1.0f) ? 2.0f * (E - sqrtf(E)) : (E - 1.0f);
                    t = fminf(fmaxf(t + d / fc, 0.0f), Mv[side]);
                }
                res[side] = -t;
            } else {
                // root > 0: g(u) = 1024u + S + sum_{m<=u}(u - m) = 1
                float u = (1.0f - Sv[side]) * (1.0f / 1024.0f);
#pragma unroll 1
                for (int s = 0; s < 12; ++s) {
                    float s2 = 0.f; int c2 = 0;
#pragma unroll
                    for (int j = 0; j < 16; ++j) {
                        bool pr = (m[j] <= u);
                        c2 += (int)__popcll(__ballot(pr));
                        s2 += pr ? m[j] : 0.0f;
                    }
                    s2 = wave_sum(s2);
                    u = (1.0f - Sv[side] + s2) / (1024.0f + (float)c2);
                }
                res[side] = u;
            }
        }
        up_out = res[0];
        um_out = res[1];
    }

    if (lane == 0) out[(size_t)b * NF + f] = fmaxf(up_out - um_out, 0.0f);
}

extern "C" void kernel_launch(void* const* d_in, const int* in_sizes, int n_in,
                              void* d_out, int out_size, void* d_ws, size_t ws_size,
                              hipStream_t stream) {
    const float* x = (const float*)d_in[0];   // 32 x 1024
    const float* W = (const float*)d_in[1];   // 1024 x 512
    float* out = (float*)d_out;               // 32 x 512

    const size_t wt_bytes = (size_t)NN * NF * sizeof(float);
    int use_wt = (ws_size >= wt_bytes) ? 1 : 0;
    float* Wt = (float*)d_ws;

    if (use_wt) {
        dim3 g(NN / 32, NF / 32);  // 32 x 16
        transpose_w_k<<<g, 256, 0, stream>>>(W, Wt);
    }
    spike_main_k<<<NB * (NF / 4), 256, 0, stream>>>(x, W, Wt, use_wt, out);
}

// Round 4
// 33.372 us; speedup vs baseline: 3.0484x; 3.0484x over previous
//
#include <hip/hip_runtime.h>
#include <math.h>

#define NB 32
#define NN 1024
#define NF 512

// ---------------- transpose W[NN][NF] -> Wt[NF][NN] ----------------
__global__ __launch_bounds__(256) void transpose_w_k(const float* __restrict__ W,
                                                     float* __restrict__ Wt) {
    __shared__ float tile[32][33];
    int n0 = blockIdx.x * 32;
    int f0 = blockIdx.y * 32;
    int tx = threadIdx.x & 31;
    int ty = threadIdx.x >> 5;  // 0..7
#pragma unroll
    for (int r = 0; r < 32; r += 8) {
        tile[ty + r][tx] = W[(n0 + ty + r) * NF + (f0 + tx)];
    }
    __syncthreads();
#pragma unroll
    for (int r = 0; r < 32; r += 8) {
        Wt[(f0 + ty + r) * NN + (n0 + tx)] = tile[tx][ty + r];
    }
}

// xor-butterfly: every lane ends with the bitwise-identical value
__device__ __forceinline__ float wave_sum(float v) {
#pragma unroll
    for (int d = 1; d < 64; d <<= 1) v += __shfl_xor(v, d, 64);
    return v;
}
__device__ __forceinline__ float wave_max(float v) {
#pragma unroll
    for (int d = 1; d < 64; d <<= 1) v = fmaxf(v, __shfl_xor(v, d, 64));
    return v;
}

// Cold-path exact solver, macro-expanded so NO pointer to the register arrays
// is ever taken (runtime-indexed pointers would spill mp/mm to scratch — this
// was the round-3 regression: WRITE_SIZE 128KB -> 131MB of spill traffic).
#define COLD_SOLVE(MARR, SV, MV, NEGV, RESV)                                     \
    if (NEGV) {                                                                  \
        float t_ = fminf(fmaxf(2.0f * (SV - sqrtf(SV)) * (1.0f/1024.0f), 0.0f), MV); \
        _Pragma("unroll 1")                                                      \
        for (int s_ = 0; s_ < 20; ++s_) {                                        \
            float ss_ = 0.f; int c_ = 0;                                         \
            _Pragma("unroll")                                                    \
            for (int j_ = 0; j_ < 16; ++j_) {                                    \
                bool pr_ = (MARR[j_] >= t_);                                     \
                c_ += (int)__popcll(__ballot(pr_));                              \
                ss_ += pr_ ? MARR[j_] : 0.0f;                                    \
            }                                                                    \
            ss_ = wave_sum(ss_);                                                 \
            float fc_ = (float)c_;                                               \
            float E_ = ss_ - t_ * fc_;                                           \
            float d_ = (E_ >= 1.0f) ? 2.0f * (E_ - sqrtf(E_)) : (E_ - 1.0f);     \
            t_ = fminf(fmaxf(t_ + d_ / fc_, 0.0f), MV);                          \
        }                                                                        \
        RESV = -t_;                                                              \
    } else {                                                                     \
        float u_ = (1.0f - SV) * (1.0f/1024.0f);                                 \
        _Pragma("unroll 1")                                                      \
        for (int s_ = 0; s_ < 12; ++s_) {                                        \
            float s2_ = 0.f; int c2_ = 0;                                        \
            _Pragma("unroll")                                                    \
            for (int j_ = 0; j_ < 16; ++j_) {                                    \
                bool pr_ = (MARR[j_] <= u_);                                     \
                c2_ += (int)__popcll(__ballot(pr_));                             \
                s2_ += pr_ ? MARR[j_] : 0.0f;                                    \
            }                                                                    \
            s2_ = wave_sum(s2_);                                                 \
            u_ = (1.0f - SV + s2_) / (1024.0f + (float)c2_);                     \
        }                                                                        \
        RESV = u_;                                                               \
    }

// One wave per output (b,f). Output = relu(u_p - u_m) where u_s is the root of
//   g(u) = sum_n [ relu(u - m_n) + relu(u + m_n) ] = 1,
// m = |x + 0.5W| (plus side), m = |x - 0.5W| (minus side).
// Negative-root regime (Sum m >= 1, always true here): solve F(t) = 1 with
//   F(t) = sum relu(m - t), u = -t, t in [0, max m]. F convex piecewise-linear,
// near-quadratic for this data => hybrid sqrt-model/Newton, fixed 5 sweeps.
__global__ __launch_bounds__(256) void spike_main_k(const float* __restrict__ x,
                                                    const float* __restrict__ W,
                                                    const float* __restrict__ Wt,
                                                    int use_wt,
                                                    float* __restrict__ out) {
    int bid  = blockIdx.x;
    int b    = bid >> 7;
    int fg   = bid & 127;
    int wave = threadIdx.x >> 6;
    int lane = threadIdx.x & 63;
    int f    = fg * 4 + wave;

    float mp[16], mm[16];
    float sp0 = 0.f, sm0 = 0.f, xp0 = 0.f, xm0 = 0.f;

    if (use_wt) {
        const float4* x4 = reinterpret_cast<const float4*>(x + (size_t)b * NN);
        const float4* w4 = reinterpret_cast<const float4*>(Wt + (size_t)f * NN);
#pragma unroll
        for (int j = 0; j < 4; ++j) {
            float4 xv = x4[lane + 64 * j];
            float4 wv = w4[lane + 64 * j];
            float ap, am;
            ap = fabsf(xv.x + 0.5f * wv.x); am = fabsf(xv.x - 0.5f * wv.x);
            mp[4*j+0] = ap; mm[4*j+0] = am; sp0 += ap; sm0 += am;
            xp0 = fmaxf(xp0, ap); xm0 = fmaxf(xm0, am);
            ap = fabsf(xv.y + 0.5f * wv.y); am = fabsf(xv.y - 0.5f * wv.y);
            mp[4*j+1] = ap; mm[4*j+1] = am; sp0 += ap; sm0 += am;
            xp0 = fmaxf(xp0, ap); xm0 = fmaxf(xm0, am);
            ap = fabsf(xv.z + 0.5f * wv.z); am = fabsf(xv.z - 0.5f * wv.z);
            mp[4*j+2] = ap; mm[4*j+2] = am; sp0 += ap; sm0 += am;
            xp0 = fmaxf(xp0, ap); xm0 = fmaxf(xm0, am);
            ap = fabsf(xv.w + 0.5f * wv.w); am = fabsf(xv.w - 0.5f * wv.w);
            mp[4*j+3] = ap; mm[4*j+3] = am; sp0 += ap; sm0 += am;
            xp0 = fmaxf(xp0, ap); xm0 = fmaxf(xm0, am);
        }
    } else {
#pragma unroll
        for (int j = 0; j < 16; ++j) {
            int n = lane + 64 * j;
            float xv = x[(size_t)b * NN + n];
            float wv = W[(size_t)n * NF + f];
            float ap = fabsf(xv + 0.5f * wv);
            float am = fabsf(xv - 0.5f * wv);
            mp[j] = ap; mm[j] = am;
            sp0 += ap; sm0 += am;
            xp0 = fmaxf(xp0, ap); xm0 = fmaxf(xm0, am);
        }
    }
    float Sp = wave_sum(sp0);
    float Sm = wave_sum(sm0);
    float Mp = wave_max(xp0);
    float Mm = wave_max(xm0);

    const bool neg_p = (Sp >= 1.0f);
    const bool neg_m = (Sm >= 1.0f);

    float up_out, um_out;

    if (neg_p && neg_m) {
        // ---- fast path (always taken for this data): both roots <= 0 ----
        // warm start from the quadratic model at t=0: F(0)=S, F'(0)=-1024
        float tp = fminf(fmaxf(2.0f * (Sp - sqrtf(Sp)) * (1.0f / 1024.0f), 0.0f), Mp);
        float tm = fminf(fmaxf(2.0f * (Sm - sqrtf(Sm)) * (1.0f / 1024.0f), 0.0f), Mm);
#pragma unroll
        for (int s = 0; s < 5; ++s) {
            float ssp = 0.f, ssm = 0.f;
            int cp = 0, cm = 0;
#pragma unroll
            for (int j = 0; j < 16; ++j) {
                bool prp = (mp[j] >= tp);
                bool prm = (mm[j] >= tm);
                cp += (int)__popcll(__ballot(prp));   // SALU pipe
                cm += (int)__popcll(__ballot(prm));
                ssp += prp ? mp[j] : 0.0f;
                ssm += prm ? mm[j] : 0.0f;
            }
            ssp = wave_sum(ssp);
            ssm = wave_sum(ssm);
            float fcp = (float)cp, fcm = (float)cm;     // >= 1 (t <= M)
            float Ep = ssp - tp * fcp;                  // F(tp) >= 0
            float Em = ssm - tm * fcm;
            float dp = (Ep >= 1.0f) ? 2.0f * (Ep - sqrtf(Ep)) : (Ep - 1.0f);
            float dm = (Em >= 1.0f) ? 2.0f * (Em - sqrtf(Em)) : (Em - 1.0f);
            tp = fminf(fmaxf(tp + dp / fcp, 0.0f), Mp);
            tm = fminf(fmaxf(tm + dm / fcm, 0.0f), Mm);
        }
        up_out = -tp;
        um_out = -tm;
    } else {
        // ---- cold path: exact general solver, fixed counts, macro-expanded ----
        COLD_SOLVE(mp, Sp, Mp, neg_p, up_out);
        COLD_SOLVE(mm, Sm, Mm, neg_m, um_out);
    }

    if (lane == 0) out[(size_t)b * NF + f] = fmaxf(up_out - um_out, 0.0f);
}

extern "C" void kernel_launch(void* const* d_in, const int* in_sizes, int n_in,
                              void* d_out, int out_size, void* d_ws, size_t ws_size,
                              hipStream_t stream) {
    const float* x = (const float*)d_in[0];   // 32 x 1024
    const float* W = (const float*)d_in[1];   // 1024 x 512
    float* out = (float*)d_out;               // 32 x 512

    const size_t wt_bytes = (size_t)NN * NF * sizeof(float);
    int use_wt = (ws_size >= wt_bytes) ? 1 : 0;
    float* Wt = (float*)d_ws;

    if (use_wt) {
        dim3 g(NN / 32, NF / 32);  // 32 x 16
        transpose_w_k<<<g, 256, 0, stream>>>(W, Wt);
    }
    spike_main_k<<<NB * (NF / 4), 256, 0, stream>>>(x, W, Wt, use_wt, out);
}

// Round 6
// 32.984 us; speedup vs baseline: 3.0843x; 1.0118x over previous
//
#include <hip/hip_runtime.h>
#include <math.h>

#define NB 32
#define NN 1024
#define NF 512

// ---------------- transpose W[NN][NF] -> Wt[NF][NN] ----------------
__global__ __launch_bounds__(256) void transpose_w_k(const float* __restrict__ W,
                                                     float* __restrict__ Wt) {
    __shared__ float tile[32][33];
    int n0 = blockIdx.x * 32;
    int f0 = blockIdx.y * 32;
    int tx = threadIdx.x & 31;
    int ty = threadIdx.x >> 5;  // 0..7
#pragma unroll
    for (int r = 0; r < 32; r += 8) {
        tile[ty + r][tx] = W[(n0 + ty + r) * NF + (f0 + tx)];
    }
    __syncthreads();
#pragma unroll
    for (int r = 0; r < 32; r += 8) {
        Wt[(f0 + ty + r) * NN + (n0 + tx)] = tile[tx][ty + r];
    }
}

// xor-butterfly: every lane ends with the bitwise-identical value
__device__ __forceinline__ float wave_sum(float v) {
#pragma unroll
    for (int d = 1; d < 64; d <<= 1) v += __shfl_xor(v, d, 64);
    return v;
}
__device__ __forceinline__ float wave_max(float v) {
#pragma unroll
    for (int d = 1; d < 64; d <<= 1) v = fmaxf(v, __shfl_xor(v, d, 64));
    return v;
}

__device__ __forceinline__ float fast_sqrt(float v) { return __builtin_amdgcn_sqrtf(v); }
__device__ __forceinline__ float fast_rcp(float v)  { return __builtin_amdgcn_rcpf(v); }

// Cold-path exact solver, macro-expanded so NO pointer to the register arrays
// is ever taken (runtime-indexed pointers spill mp/mm to scratch — round-3 bug).
#define COLD_SOLVE(MARR, SV, MV, NEGV, RESV)                                     \
    if (NEGV) {                                                                  \
        float t_ = fminf(fmaxf(2.0f * (SV - fast_sqrt(SV)) * (1.0f/1024.0f), 0.0f), MV); \
        _Pragma("unroll 1")                                                      \
        for (int s_ = 0; s_ < 20; ++s_) {                                        \
            float ss_ = 0.f; int c_ = 0;                                         \
            _Pragma("unroll")                                                    \
            for (int j_ = 0; j_ < 16; ++j_) {                                    \
                bool pr_ = (MARR[j_] >= t_);                                     \
                c_ += (int)__popcll(__ballot(pr_));                              \
                ss_ += pr_ ? MARR[j_] : 0.0f;                                    \
            }                                                                    \
            ss_ = wave_sum(ss_);                                                 \
            float fc_ = (float)c_;                                               \
            float E_ = ss_ - t_ * fc_;                                           \
            float d_ = (E_ >= 1.0f) ? 2.0f * (E_ - fast_sqrt(E_)) : (E_ - 1.0f); \
            t_ = fminf(fmaxf(t_ + d_ * fast_rcp(fc_), 0.0f), MV);                \
        }                                                                        \
        RESV = -t_;                                                              \
    } else {                                                                     \
        float u_ = (1.0f - SV) * (1.0f/1024.0f);                                 \
        _Pragma("unroll 1")                                                      \
        for (int s_ = 0; s_ < 12; ++s_) {                                        \
            float s2_ = 0.f; int c2_ = 0;                                        \
            _Pragma("unroll")                                                    \
            for (int j_ = 0; j_ < 16; ++j_) {                                    \
                bool pr_ = (MARR[j_] <= u_);                                     \
                c2_ += (int)__popcll(__ballot(pr_));                             \
                s2_ += pr_ ? MARR[j_] : 0.0f;                                    \
            }                                                                    \
            s2_ = wave_sum(s2_);                                                 \
            u_ = (1.0f - SV + s2_) * fast_rcp(1024.0f + (float)c2_);             \
        }                                                                        \
        RESV = u_;                                                               \
    }

// One wave per output (b,f). Output = relu(u_p - u_m) where u_s is the root of
//   g(u) = sum_n [ relu(u - m_n) + relu(u + m_n) ] = 1,
// m = |x + 0.5W| (plus side), m = |x - 0.5W| (minus side).
// Negative-root regime (Sum m >= 1, always true here): solve F(t) = 1 with
//   F(t) = sum relu(m - t), u = -t, t in [0, max m]. F convex piecewise-linear,
// near-quadratic for this data => hybrid sqrt-model/Newton.
// FIXED 5 SWEEPS: 3 sweeps measured absmax 7.6e-4 (> 4.27e-4 threshold, round 5
// FAIL); 5 sweeps measured 6.1e-5 = converged floor (rounds 1-4). ~3.5x/sweep
// decay => 4 sweeps only ~2x margin; keep 5.
__global__ __launch_bounds__(256) void spike_main_k(const float* __restrict__ x,
                                                    const float* __restrict__ W,
                                                    const float* __restrict__ Wt,
                                                    int use_wt,
                                                    float* __restrict__ out) {
    int bid  = blockIdx.x;
    int b    = bid >> 7;
    int fg   = bid & 127;
    int wave = threadIdx.x >> 6;
    int lane = threadIdx.x & 63;
    int f    = fg * 4 + wave;

    float mp[16], mm[16];
    float sp0 = 0.f, sm0 = 0.f, xp0 = 0.f, xm0 = 0.f;

    if (use_wt) {
        const float4* x4 = reinterpret_cast<const float4*>(x + (size_t)b * NN);
        const float4* w4 = reinterpret_cast<const float4*>(Wt + (size_t)f * NN);
#pragma unroll
        for (int j = 0; j < 4; ++j) {
            float4 xv = x4[lane + 64 * j];
            float4 wv = w4[lane + 64 * j];
            float ap, am;
            ap = fabsf(xv.x + 0.5f * wv.x); am = fabsf(xv.x - 0.5f * wv.x);
            mp[4*j+0] = ap; mm[4*j+0] = am; sp0 += ap; sm0 += am;
            xp0 = fmaxf(xp0, ap); xm0 = fmaxf(xm0, am);
            ap = fabsf(xv.y + 0.5f * wv.y); am = fabsf(xv.y - 0.5f * wv.y);
            mp[4*j+1] = ap; mm[4*j+1] = am; sp0 += ap; sm0 += am;
            xp0 = fmaxf(xp0, ap); xm0 = fmaxf(xm0, am);
            ap = fabsf(xv.z + 0.5f * wv.z); am = fabsf(xv.z - 0.5f * wv.z);
            mp[4*j+2] = ap; mm[4*j+2] = am; sp0 += ap; sm0 += am;
            xp0 = fmaxf(xp0, ap); xm0 = fmaxf(xm0, am);
            ap = fabsf(xv.w + 0.5f * wv.w); am = fabsf(xv.w - 0.5f * wv.w);
            mp[4*j+3] = ap; mm[4*j+3] = am; sp0 += ap; sm0 += am;
            xp0 = fmaxf(xp0, ap); xm0 = fmaxf(xm0, am);
        }
    } else {
#pragma unroll
        for (int j = 0; j < 16; ++j) {
            int n = lane + 64 * j;
            float xv = x[(size_t)b * NN + n];
            float wv = W[(size_t)n * NF + f];
            float ap = fabsf(xv + 0.5f * wv);
            float am = fabsf(xv - 0.5f * wv);
            mp[j] = ap; mm[j] = am;
            sp0 += ap; sm0 += am;
            xp0 = fmaxf(xp0, ap); xm0 = fmaxf(xm0, am);
        }
    }

    // Pin the magnitude arrays into VGPRs: without this the compiler keeps
    // VGPR_Count ~28-36 by REMATERIALIZING mp/mm (reload x/Wt + fma + abs)
    // inside every sweep — ~2x the expected VALU work. The empty asm makes
    // each value opaque (can't be recomputed), forcing it to stay resident.
#pragma unroll
    for (int j = 0; j < 16; ++j) {
        asm volatile("" : "+v"(mp[j]), "+v"(mm[j]));
    }

    float Sp = wave_sum(sp0);
    float Sm = wave_sum(sm0);
    float Mp = wave_max(xp0);
    float Mm = wave_max(xm0);

    const bool neg_p = (Sp >= 1.0f);
    const bool neg_m = (Sm >= 1.0f);

    float up_out, um_out;

    if (neg_p && neg_m) {
        // ---- fast path (always taken for this data): both roots <= 0 ----
        // warm start from the quadratic model at t=0: F(0)=S, F'(0)=-1024
        float tp = fminf(fmaxf(2.0f * (Sp - fast_sqrt(Sp)) * (1.0f / 1024.0f), 0.0f), Mp);
        float tm = fminf(fmaxf(2.0f * (Sm - fast_sqrt(Sm)) * (1.0f / 1024.0f), 0.0f), Mm);
#pragma unroll
        for (int s = 0; s < 5; ++s) {
            float ssp = 0.f, ssm = 0.f;
            int cp = 0, cm = 0;
#pragma unroll
            for (int j = 0; j < 16; ++j) {
                bool prp = (mp[j] >= tp);
                bool prm = (mm[j] >= tm);
                cp += (int)__popcll(__ballot(prp));   // count via SALU popc
                cm += (int)__popcll(__ballot(prm));
                ssp += prp ? mp[j] : 0.0f;
                ssm += prm ? mm[j] : 0.0f;
            }
            ssp = wave_sum(ssp);
            ssm = wave_sum(ssm);
            float fcp = (float)cp, fcm = (float)cm;     // >= 1 (t <= M)
            float Ep = ssp - tp * fcp;                  // F(tp) >= 0
            float Em = ssm - tm * fcm;
            float dp = (Ep >= 1.0f) ? 2.0f * (Ep - fast_sqrt(Ep)) : (Ep - 1.0f);
            float dm = (Em >= 1.0f) ? 2.0f * (Em - fast_sqrt(Em)) : (Em - 1.0f);
            tp = fminf(fmaxf(tp + dp * fast_rcp(fcp), 0.0f), Mp);
            tm = fminf(fmaxf(tm + dm * fast_rcp(fcm), 0.0f), Mm);
        }
        up_out = -tp;
        um_out = -tm;
    } else {
        // ---- cold path: exact general solver, fixed counts, macro-expanded ----
        COLD_SOLVE(mp, Sp, Mp, neg_p, up_out);
        COLD_SOLVE(mm, Sm, Mm, neg_m, um_out);
    }

    if (lane == 0) out[(size_t)b * NF + f] = fmaxf(up_out - um_out, 0.0f);
}

extern "C" void kernel_launch(void* const* d_in, const int* in_sizes, int n_in,
                              void* d_out, int out_size, void* d_ws, size_t ws_size,
                              hipStream_t stream) {
    const float* x = (const float*)d_in[0];   // 32 x 1024
    const float* W = (const float*)d_in[1];   // 1024 x 512
    float* out = (float*)d_out;               // 32 x 512

    const size_t wt_bytes = (size_t)NN * NF * sizeof(float);
    int use_wt = (ws_size >= wt_bytes) ? 1 : 0;
    float* Wt = (float*)d_ws;

    if (use_wt) {
        dim3 g(NN / 32, NF / 32);  // 32 x 16
        transpose_w_k<<<g, 256, 0, stream>>>(W, Wt);
    }
    spike_main_k<<<NB * (NF / 4), 256, 0, stream>>>(x, W, Wt, use_wt, out);
}

// Round 7
// 31.068 us; speedup vs baseline: 3.2744x; 1.0617x over previous
//
#include <hip/hip_runtime.h>
#include <math.h>

#define NB 32
#define NN 1024
#define NF 512

// ---------------- transpose W[NN][NF] -> Wt[NF][NN] ----------------
__global__ __launch_bounds__(256) void transpose_w_k(const float* __restrict__ W,
                                                     float* __restrict__ Wt) {
    __shared__ float tile[32][33];
    int n0 = blockIdx.x * 32;
    int f0 = blockIdx.y * 32;
    int tx = threadIdx.x & 31;
    int ty = threadIdx.x >> 5;  // 0..7
#pragma unroll
    for (int r = 0; r < 32; r += 8) {
        tile[ty + r][tx] = W[(n0 + ty + r) * NF + (f0 + tx)];
    }
    __syncthreads();
#pragma unroll
    for (int r = 0; r < 32; r += 8) {
        Wt[(f0 + ty + r) * NN + (n0 + tx)] = tile[tx][ty + r];
    }
}

// ---------------- DPP wave64 reductions (VALU-only, no DS pipe) ----------------
// Butterfly chains via __shfl_xor lower to ds_swizzle/ds_bpermute: ~30-40cy DS
// latency x 6 dependent levels ~= 240cy per reduction, serializing every sweep.
// DPP row ops are full-rate VALU (~4-8cy): quad_perm xor1, xor2, half_mirror,
// mirror, bcast15, bcast31 -> total in lane 63 -> readlane = wave-uniform scalar.
#define DPP_XOR1        0xB1   // quad_perm [1,0,3,2]
#define DPP_XOR2        0x4E   // quad_perm [2,3,0,1]
#define DPP_HALF_MIRROR 0x141
#define DPP_MIRROR      0x140
#define DPP_BCAST15     0x142
#define DPP_BCAST31     0x143

template <int CTRL>
__device__ __forceinline__ float dpp_mov(float v) {
    return __int_as_float(__builtin_amdgcn_update_dpp(
        0, __float_as_int(v), CTRL, 0xf, 0xf, true));
}

// returns the wave-wide sum as a wave-uniform (sgpr-resident) value
__device__ __forceinline__ float wave_sum_u(float v) {
    v += dpp_mov<DPP_XOR1>(v);
    v += dpp_mov<DPP_XOR2>(v);
    v += dpp_mov<DPP_HALF_MIRROR>(v);
    v += dpp_mov<DPP_MIRROR>(v);
    v += dpp_mov<DPP_BCAST15>(v);   // invalid lanes read 0 (bound_ctrl)
    v += dpp_mov<DPP_BCAST31>(v);
    return __int_as_float(__builtin_amdgcn_readlane(__float_as_int(v), 63));
}
// wave-wide max of NON-NEGATIVE values (bound_ctrl zeros are identity for max)
__device__ __forceinline__ float wave_max_u(float v) {
    v = fmaxf(v, dpp_mov<DPP_XOR1>(v));
    v = fmaxf(v, dpp_mov<DPP_XOR2>(v));
    v = fmaxf(v, dpp_mov<DPP_HALF_MIRROR>(v));
    v = fmaxf(v, dpp_mov<DPP_MIRROR>(v));
    v = fmaxf(v, dpp_mov<DPP_BCAST15>(v));
    v = fmaxf(v, dpp_mov<DPP_BCAST31>(v));
    return __int_as_float(__builtin_amdgcn_readlane(__float_as_int(v), 63));
}

__device__ __forceinline__ float fast_sqrt(float v) { return __builtin_amdgcn_sqrtf(v); }
__device__ __forceinline__ float fast_rcp(float v)  { return __builtin_amdgcn_rcpf(v); }

// Cold-path exact solver, macro-expanded so NO pointer to the register arrays
// is ever taken (runtime-indexed pointers spill mp/mm to scratch — round-3 bug).
#define COLD_SOLVE(MARR, SV, MV, NEGV, RESV)                                     \
    if (NEGV) {                                                                  \
        float t_ = fminf(fmaxf(2.0f * (SV - fast_sqrt(SV)) * (1.0f/1024.0f), 0.0f), MV); \
        _Pragma("unroll 1")                                                      \
        for (int s_ = 0; s_ < 20; ++s_) {                                        \
            float ss_ = 0.f; int c_ = 0;                                         \
            _Pragma("unroll")                                                    \
            for (int j_ = 0; j_ < 16; ++j_) {                                    \
                bool pr_ = (MARR[j_] >= t_);                                     \
                c_ += (int)__popcll(__ballot(pr_));                              \
                ss_ += pr_ ? MARR[j_] : 0.0f;                                    \
            }                                                                    \
            ss_ = wave_sum_u(ss_);                                               \
            float fc_ = (float)c_;                                               \
            float E_ = ss_ - t_ * fc_;                                           \
            float d_ = (E_ >= 1.0f) ? 2.0f * (E_ - fast_sqrt(E_)) : (E_ - 1.0f); \
            t_ = fminf(fmaxf(t_ + d_ * fast_rcp(fc_), 0.0f), MV);                \
        }                                                                        \
        RESV = -t_;                                                              \
    } else {                                                                     \
        float u_ = (1.0f - SV) * (1.0f/1024.0f);                                 \
        _Pragma("unroll 1")                                                      \
        for (int s_ = 0; s_ < 12; ++s_) {                                        \
            float s2_ = 0.f; int c2_ = 0;                                        \
            _Pragma("unroll")                                                    \
            for (int j_ = 0; j_ < 16; ++j_) {                                    \
                bool pr_ = (MARR[j_] <= u_);                                     \
                c2_ += (int)__popcll(__ballot(pr_));                             \
                s2_ += pr_ ? MARR[j_] : 0.0f;                                    \
            }                                                                    \
            s2_ = wave_sum_u(s2_);                                               \
            u_ = (1.0f - SV + s2_) * fast_rcp(1024.0f + (float)c2_);             \
        }                                                                        \
        RESV = u_;                                                               \
    }

// One wave per output (b,f). Output = relu(u_p - u_m) where u_s is the root of
//   g(u) = sum_n [ relu(u - m_n) + relu(u + m_n) ] = 1,
// m = |x + 0.5W| (plus side), m = |x - 0.5W| (minus side).
// Negative-root regime (Sum m >= 1, always true here): solve F(t) = 1 with
//   F(t) = sum relu(m - t), u = -t, t in [0, max m]. F convex piecewise-linear,
// near-quadratic for this data => hybrid sqrt-model/Newton.
// FIXED 5 SWEEPS: 3 sweeps measured absmax 7.6e-4 (round-5 FAIL vs 4.27e-4);
// 5 sweeps measured 6.1e-5 converged floor (rounds 1-4,6). Keep 5.
__global__ __launch_bounds__(256) void spike_main_k(const float* __restrict__ x,
                                                    const float* __restrict__ W,
                                                    const float* __restrict__ Wt,
                                                    int use_wt,
                                                    float* __restrict__ out) {
    int bid  = blockIdx.x;
    int b    = bid >> 7;
    int fg   = bid & 127;
    int wave = threadIdx.x >> 6;
    int lane = threadIdx.x & 63;
    int f    = fg * 4 + wave;

    float mp[16], mm[16];
    float sp0 = 0.f, sm0 = 0.f, xp0 = 0.f, xm0 = 0.f;

    if (use_wt) {
        const float4* x4 = reinterpret_cast<const float4*>(x + (size_t)b * NN);
        const float4* w4 = reinterpret_cast<const float4*>(Wt + (size_t)f * NN);
#pragma unroll
        for (int j = 0; j < 4; ++j) {
            float4 xv = x4[lane + 64 * j];
            float4 wv = w4[lane + 64 * j];
            float ap, am;
            ap = fabsf(xv.x + 0.5f * wv.x); am = fabsf(xv.x - 0.5f * wv.x);
            mp[4*j+0] = ap; mm[4*j+0] = am; sp0 += ap; sm0 += am;
            xp0 = fmaxf(xp0, ap); xm0 = fmaxf(xm0, am);
            ap = fabsf(xv.y + 0.5f * wv.y); am = fabsf(xv.y - 0.5f * wv.y);
            mp[4*j+1] = ap; mm[4*j+1] = am; sp0 += ap; sm0 += am;
            xp0 = fmaxf(xp0, ap); xm0 = fmaxf(xm0, am);
            ap = fabsf(xv.z + 0.5f * wv.z); am = fabsf(xv.z - 0.5f * wv.z);
            mp[4*j+2] = ap; mm[4*j+2] = am; sp0 += ap; sm0 += am;
            xp0 = fmaxf(xp0, ap); xm0 = fmaxf(xm0, am);
            ap = fabsf(xv.w + 0.5f * wv.w); am = fabsf(xv.w - 0.5f * wv.w);
            mp[4*j+3] = ap; mm[4*j+3] = am; sp0 += ap; sm0 += am;
            xp0 = fmaxf(xp0, ap); xm0 = fmaxf(xm0, am);
        }
    } else {
#pragma unroll
        for (int j = 0; j < 16; ++j) {
            int n = lane + 64 * j;
            float xv = x[(size_t)b * NN + n];
            float wv = W[(size_t)n * NF + f];
            float ap = fabsf(xv + 0.5f * wv);
            float am = fabsf(xv - 0.5f * wv);
            mp[j] = ap; mm[j] = am;
            sp0 += ap; sm0 += am;
            xp0 = fmaxf(xp0, ap); xm0 = fmaxf(xm0, am);
        }
    }

    // keep the magnitude arrays opaque (prevents rematerialization; cheap)
#pragma unroll
    for (int j = 0; j < 16; ++j) {
        asm volatile("" : "+v"(mp[j]), "+v"(mm[j]));
    }

    float Sp = wave_sum_u(sp0);
    float Sm = wave_sum_u(sm0);
    float Mp = wave_max_u(xp0);
    float Mm = wave_max_u(xm0);

    const bool neg_p = (Sp >= 1.0f);
    const bool neg_m = (Sm >= 1.0f);

    float up_out, um_out;

    if (neg_p && neg_m) {
        // ---- fast path (always taken for this data): both roots <= 0 ----
        // warm start from the quadratic model at t=0: F(0)=S, F'(0)=-1024
        float tp = fminf(fmaxf(2.0f * (Sp - fast_sqrt(Sp)) * (1.0f / 1024.0f), 0.0f), Mp);
        float tm = fminf(fmaxf(2.0f * (Sm - fast_sqrt(Sm)) * (1.0f / 1024.0f), 0.0f), Mm);
#pragma unroll
        for (int s = 0; s < 5; ++s) {
            float ssp = 0.f, ssm = 0.f;
            int cp = 0, cm = 0;
#pragma unroll
            for (int j = 0; j < 16; ++j) {
                bool prp = (mp[j] >= tp);   // tp/tm wave-uniform -> sgpr operand
                bool prm = (mm[j] >= tm);
                cp += (int)__popcll(__ballot(prp));   // count on SALU popc
                cm += (int)__popcll(__ballot(prm));
                ssp += prp ? mp[j] : 0.0f;
                ssm += prm ? mm[j] : 0.0f;
            }
            ssp = wave_sum_u(ssp);   // DPP tree, ~40cy, uniform result
            ssm = wave_sum_u(ssm);
            float fcp = (float)cp, fcm = (float)cm;     // >= 1 (t <= M)
            float Ep = ssp - tp * fcp;                  // F(tp) >= 0
            float Em = ssm - tm * fcm;
            float dp = (Ep >= 1.0f) ? 2.0f * (Ep - fast_sqrt(Ep)) : (Ep - 1.0f);
            float dm = (Em >= 1.0f) ? 2.0f * (Em - fast_sqrt(Em)) : (Em - 1.0f);
            tp = fminf(fmaxf(tp + dp * fast_rcp(fcp), 0.0f), Mp);
            tm = fminf(fmaxf(tm + dm * fast_rcp(fcm), 0.0f), Mm);
        }
        up_out = -tp;
        um_out = -tm;
    } else {
        // ---- cold path: exact general solver, fixed counts, macro-expanded ----
        COLD_SOLVE(mp, Sp, Mp, neg_p, up_out);
        COLD_SOLVE(mm, Sm, Mm, neg_m, um_out);
    }

    if (lane == 0) out[(size_t)b * NF + f] = fmaxf(up_out - um_out, 0.0f);
}

extern "C" void kernel_launch(void* const* d_in, const int* in_sizes, int n_in,
                              void* d_out, int out_size, void* d_ws, size_t ws_size,
                              hipStream_t stream) {
    const float* x = (const float*)d_in[0];   // 32 x 1024
    const float* W = (const float*)d_in[1];   // 1024 x 512
    float* out = (float*)d_out;               // 32 x 512

    const size_t wt_bytes = (size_t)NN * NF * sizeof(float);
    int use_wt = (ws_size >= wt_bytes) ? 1 : 0;
    float* Wt = (float*)d_ws;

    if (use_wt) {
        dim3 g(NN / 32, NF / 32);  // 32 x 16
        transpose_w_k<<<g, 256, 0, stream>>>(W, Wt);
    }
    spike_main_k<<<NB * (NF / 4), 256, 0, stream>>>(x, W, Wt, use_wt, out);
}